// Round 1
// 2861.213 us; speedup vs baseline: 1.1288x; 1.1288x over previous
//
#include <hip/hip_runtime.h>

#define NTOK 49
#define DIMC 384
#define NH 12
#define HD 32
#define NWM 64
#define SCALE 0.17677669529663687f  // 1/sqrt(32)

// per-head LDS region (ushort units): q/out [49][40], k [49][40], v^T [32][72]
#define HSTRIDE 6224
#define KOFF 1960
#define VOFF 3920

typedef __attribute__((ext_vector_type(8))) __bf16 bf16x8;
typedef __attribute__((ext_vector_type(4))) float f32x4;

__device__ __forceinline__ unsigned short f2b(float f) {
  union { float f; unsigned u; } v; v.f = f;
  unsigned r = v.u + 0x7fffu + ((v.u >> 16) & 1u);  // round-to-nearest-even
  return (unsigned short)(r >> 16);
}

union BF8 { unsigned short u[8]; bf16x8 v; };

// ---------------- prep: weight transpose->bf16, bias gather ----------------
__global__ void prep_kernel(const float* __restrict__ qkv_w,
                            const float* __restrict__ out_w,
                            const float* __restrict__ table,
                            const int* __restrict__ rel_index,
                            unsigned short* __restrict__ wtq,   // [1152][384] bf16
                            unsigned short* __restrict__ wto,   // [384][384]  bf16
                            float* __restrict__ biasM) {        // [12][49][49] f32
  int id = blockIdx.x * 256 + threadIdx.x;
  if (id < 1152 * 384) {
    int col = id / 384, k = id - col * 384;
    wtq[id] = f2b(qkv_w[k * 1152 + col]);
  } else if (id < 1152 * 384 + 384 * 384) {
    int id2 = id - 1152 * 384;
    int col = id2 / 384, k = id2 - col * 384;
    wto[id2] = f2b(out_w[k * 384 + col]);
  } else if (id < 1152 * 384 + 384 * 384 + NH * NTOK * NTOK) {
    int id3 = id - (1152 * 384 + 384 * 384);
    int h = id3 / (NTOK * NTOK), ij = id3 - h * (NTOK * NTOK);
    biasM[id3] = table[rel_index[ij] * NH + h];
  }
}

// ---------------- fully fused: qkv + attention (all heads) + out-proj ------
// 512 threads = 8 waves. LDS 149376 B -> 1 block/CU (8 waves).
// Barriers per block: 2.
__global__ __launch_bounds__(512, 2) void fused_kernel(
    const float* __restrict__ x, const float* __restrict__ mask,
    const unsigned short* __restrict__ wtq, const float* __restrict__ qkv_b,
    const float* __restrict__ biasM, const unsigned short* __restrict__ wto,
    const float* __restrict__ out_b, float* __restrict__ out) {
  __shared__ __align__(16) unsigned short smem[NH * HSTRIDE];  // 149376 B

  const int tid = threadIdx.x;
  const int lane = tid & 63;
  const int wv = tid >> 6;       // 0..7
  const int quad = lane >> 4;
  const int l16 = lane & 15;
  const int b = blockIdx.x;
  const int mt = wv & 3;         // M-tile (rows mt*16..mt*16+15)
  const int nh = wv >> 2;        // N-half

  const float* xw = x + (size_t)b * (NTOK * DIMC);

  // ---- A-fragments: this wave's 16 rows of x, f32 -> bf16, kept in regs ----
  int arow = mt * 16 + l16; arow = arow > 48 ? 48 : arow;  // clamp pad rows
  const float* xr = xw + arow * DIMC + quad * 8;
  bf16x8 afr[12];
#pragma unroll
  for (int kt = 0; kt < 12; ++kt) {
    float4 v0 = *(const float4*)(xr + kt * 32);
    float4 v1 = *(const float4*)(xr + kt * 32 + 4);
    BF8 t;
    t.u[0] = f2b(v0.x); t.u[1] = f2b(v0.y); t.u[2] = f2b(v0.z); t.u[3] = f2b(v0.w);
    t.u[4] = f2b(v1.x); t.u[5] = f2b(v1.y); t.u[6] = f2b(v1.z); t.u[7] = f2b(v1.w);
    afr[kt] = t.v;
  }

  // ---- P1: QKV GEMM, all heads. wave: Mtile mt x cols [nh*576, nh*576+576) ----
  for (int ng = 0; ng < 9; ++ng) {
    f32x4 acc[4];
#pragma unroll
    for (int t = 0; t < 4; ++t) acc[t] = (f32x4){0.f, 0.f, 0.f, 0.f};
    const int c0 = nh * 576 + ng * 64;
    for (int kt = 0; kt < 12; ++kt) {
#pragma unroll
      for (int t = 0; t < 4; ++t) {
        bf16x8 bb = *(const bf16x8*)(wtq + (size_t)(c0 + t * 16 + l16) * 384 + kt * 32 + quad * 8);
        acc[t] = __builtin_amdgcn_mfma_f32_16x16x32_bf16(afr[kt], bb, acc[t], 0, 0, 0);
      }
    }
    // epilogue: +bias, scatter to per-head q (scaled) / k / v^T as bf16
#pragma unroll
    for (int t = 0; t < 4; ++t) {
      int c = c0 + t * 16 + l16;
      int s = c / 384;                 // wave-uniform (16-col runs don't cross)
      int cc = c - s * 384;
      int h = cc >> 5, d = cc & 31;
      float bias = qkv_b[c];
      unsigned short* hb = smem + h * HSTRIDE;
#pragma unroll
      for (int r = 0; r < 4; ++r) {
        int i = mt * 16 + quad * 4 + r;
        if (i < NTOK) {
          float val = acc[t][r] + bias;
          if (s == 0)      hb[i * 40 + d] = f2b(val * SCALE);
          else if (s == 1) hb[KOFF + i * 40 + d] = f2b(val);
          else             hb[VOFF + d * 72 + i] = f2b(val);
        }
      }
    }
  }
  // zero v^T token-pad (tokens 49..63) for all heads
  for (int t = tid; t < NH * 32 * 15; t += 512) {
    int h = t / 480;
    int rem = t - h * 480;
    int d = rem / 15;
    int i = 49 + (rem - d * 15);
    smem[h * HSTRIDE + VOFF + d * 72 + i] = 0;
  }
  __syncthreads();  // barrier #1

  // ---- P2: attention, one whole head per wave, zero barriers ----
  const float* maskw = mask + (size_t)(b & (NWM - 1)) * (NTOK * NTOK);

  for (int hi = wv; hi < NH; hi += 8) {
    unsigned short* hb = smem + hi * HSTRIDE;
    unsigned short* Pb = hb;  // P overlays dead q+k (stride 72, rows<49 only)

    // S = q k^T  (full 64x64 in this wave: 16 MFMA, K=32 exactly)
    bf16x8 qf[4], kf[4];
#pragma unroll
    for (int m = 0; m < 4; ++m)
      qf[m] = *(const bf16x8*)(hb + (m * 16 + l16) * 40 + quad * 8);
#pragma unroll
    for (int n = 0; n < 4; ++n)
      kf[n] = *(const bf16x8*)(hb + KOFF + (n * 16 + l16) * 40 + quad * 8);
    f32x4 sacc[4][4];
#pragma unroll
    for (int m = 0; m < 4; ++m)
#pragma unroll
      for (int n = 0; n < 4; ++n) {
        sacc[m][n] = (f32x4){0.f, 0.f, 0.f, 0.f};
        sacc[m][n] = __builtin_amdgcn_mfma_f32_16x16x32_bf16(qf[m], kf[n], sacc[m][n], 0, 0, 0);
      }

    // in-register softmax: rows live in lanes (quad,r); cols in (n,l16)
    const float* bM = biasM + hi * (NTOK * NTOK);
    float rinv[4][4];
#pragma unroll
    for (int m = 0; m < 4; ++m) {
#pragma unroll
      for (int r = 0; r < 4; ++r) {
        int i = m * 16 + quad * 4 + r;
        bool iv = (i < NTOK);
        float sv[4];
        float mx = -1e30f;
#pragma unroll
        for (int n = 0; n < 4; ++n) {
          int j = n * 16 + l16;
          float v = -1e30f;
          if (iv && j < NTOK)
            v = sacc[m][n][r] + bM[i * NTOK + j] + maskw[i * NTOK + j];
          sv[n] = v;
          mx = fmaxf(mx, v);
        }
        mx = fmaxf(mx, __shfl_xor(mx, 1));
        mx = fmaxf(mx, __shfl_xor(mx, 2));
        mx = fmaxf(mx, __shfl_xor(mx, 4));
        mx = fmaxf(mx, __shfl_xor(mx, 8));
        float sum = 0.f;
        unsigned short pv[4];
#pragma unroll
        for (int n = 0; n < 4; ++n) {
          float e = __expf(sv[n] - mx);  // masked cols -> 0 (doubles as K-pad)
          sum += e;
          pv[n] = f2b(e);
        }
        sum += __shfl_xor(sum, 1);
        sum += __shfl_xor(sum, 2);
        sum += __shfl_xor(sum, 4);
        sum += __shfl_xor(sum, 8);
        rinv[m][r] = 1.0f / sum;
        if (iv) {
#pragma unroll
          for (int n = 0; n < 4; ++n)
            Pb[i * 72 + n * 16 + l16] = pv[n];  // unnormalized P, bf16
        }
      }
    }

    // PV: O = P v^T  (K = 64, pads are exact zeros)
    f32x4 oacc[4][2];
#pragma unroll
    for (int m = 0; m < 4; ++m)
#pragma unroll
      for (int n = 0; n < 2; ++n) oacc[m][n] = (f32x4){0.f, 0.f, 0.f, 0.f};
#pragma unroll
    for (int k0 = 0; k0 < 2; ++k0) {
      bf16x8 pf[4];
#pragma unroll
      for (int m = 0; m < 4; ++m)
        pf[m] = *(const bf16x8*)(Pb + (m * 16 + l16) * 72 + k0 * 32 + quad * 8);
#pragma unroll
      for (int n = 0; n < 2; ++n) {
        bf16x8 vf = *(const bf16x8*)(hb + VOFF + (n * 16 + l16) * 72 + k0 * 32 + quad * 8);
#pragma unroll
        for (int m = 0; m < 4; ++m)
          oacc[m][n] = __builtin_amdgcn_mfma_f32_16x16x32_bf16(pf[m], vf, oacc[m][n], 0, 0, 0);
      }
    }
    // head output slice, normalized, bf16, overlays q region: [49][40]
#pragma unroll
    for (int m = 0; m < 4; ++m)
#pragma unroll
      for (int n = 0; n < 2; ++n)
#pragma unroll
        for (int r = 0; r < 4; ++r) {
          int i = m * 16 + quad * 4 + r;
          if (i < NTOK)
            hb[i * 40 + n * 16 + l16] = f2b(oacc[m][n][r] * rinv[m][r]);
        }
  }
  __syncthreads();  // barrier #2

  // ---- P3: fused out-projection. head slices == K-chunks of A ----
  bf16x8 pa[12];
#pragma unroll
  for (int kt = 0; kt < 12; ++kt)
    pa[kt] = *(const bf16x8*)(smem + kt * HSTRIDE + (mt * 16 + l16) * 40 + quad * 8);
  f32x4 pacc[12];
#pragma unroll
  for (int t = 0; t < 12; ++t) pacc[t] = (f32x4){0.f, 0.f, 0.f, 0.f};
  const int cb = nh * 192;
  for (int kt = 0; kt < 12; ++kt) {
#pragma unroll
    for (int t = 0; t < 12; ++t) {
      bf16x8 bb = *(const bf16x8*)(wto + (size_t)(cb + t * 16 + l16) * 384 + kt * 32 + quad * 8);
      pacc[t] = __builtin_amdgcn_mfma_f32_16x16x32_bf16(pa[kt], bb, pacc[t], 0, 0, 0);
    }
  }
  float* outp = out + (size_t)b * (NTOK * DIMC);
#pragma unroll
  for (int t = 0; t < 12; ++t) {
    int c = cb + t * 16 + l16;
    float bias = out_b[c];
#pragma unroll
    for (int r = 0; r < 4; ++r) {
      int i = mt * 16 + quad * 4 + r;
      if (i < NTOK) outp[i * DIMC + c] = pacc[t][r] + bias;
    }
  }
}

extern "C" void kernel_launch(void* const* d_in, const int* in_sizes, int n_in,
                              void* d_out, int out_size, void* d_ws, size_t ws_size,
                              hipStream_t stream) {
  (void)n_in; (void)out_size; (void)ws_size;
  const float* x       = (const float*)d_in[0];
  const float* mask    = (const float*)d_in[1];
  const float* qkv_w   = (const float*)d_in[2];
  const float* qkv_b   = (const float*)d_in[3];
  const float* table   = (const float*)d_in[4];
  const int*   rel_idx = (const int*)d_in[5];
  const float* out_w   = (const float*)d_in[6];
  const float* out_b   = (const float*)d_in[7];
  float* out = (float*)d_out;

  // workspace: WTq bf16 [1152*384] | WTo bf16 [384*384] | biasM f32 [12*49*49]
  unsigned short* wtq = (unsigned short*)d_ws;
  unsigned short* wto = wtq + 1152 * 384;
  float* biasM = (float*)(wto + 384 * 384);

  const int B = in_sizes[0] / (NTOK * DIMC);  // 4096
  const int prep_total = 1152 * 384 + 384 * 384 + NH * NTOK * NTOK;
  prep_kernel<<<(prep_total + 255) / 256, 256, 0, stream>>>(
      qkv_w, out_w, table, rel_idx, wtq, wto, biasM);
  fused_kernel<<<B, 512, 0, stream>>>(x, mask, wtq, qkv_b, biasM, wto, out_b, out);
}